// Round 13
// baseline (172.036 us; speedup 1.0000x reference)
//
#include <hip/hip_runtime.h>
#include <math.h>

#define CC    64
#define BATCH 2048
#define EPS   1e-5f
#define SLOPE 0.01f

// ws layout (float indices):
#define WS_SUMR  0        // 32 replicas x 128 (c,o)
#define WS_SQR   4096     // 32 replicas x 128
#define WS_A     8192     // 128
#define WS_B     8320     // 128
#define WS_WF    8448     // 64*128 folded weights
#define WS_WB    16640    // 64 per-channel bias contribution
#define WS_LOGIT 16704    // 2048 (fallback path only)
#define WS_POOL  18944    // 2048*64*128 uint (bf16 mx | bf16 mn), 16B-aligned
#define WS_NEEDED_BYTES ((size_t)(WS_POOL + (size_t)BATCH * CC * 128) * 4)

typedef float f4v __attribute__((ext_vector_type(4), aligned(4)));
typedef float f2v __attribute__((ext_vector_type(2), aligned(4)));

__device__ inline unsigned bf16rne(float x) {
    unsigned u = __float_as_uint(x);
    return (u + 0x7fffu + ((u >> 16) & 1u)) >> 16;
}

// packed f32 FMA: acc += a*b
__device__ inline void pkfma(float2& acc, float2 a, float2 b) {
    asm("v_pk_fma_f32 %0, %1, %2, %0" : "+v"(acc) : "v"(a), "v"(b));
}
// packed f32 FMA, broadcast LO half of w: acc += a * {w.x, w.x}
__device__ inline void pkfma_l(float2& acc, float2 a, float2 w) {
    asm("v_pk_fma_f32 %0, %1, %2, %0 op_sel:[0,0,0] op_sel_hi:[1,0,1]"
        : "+v"(acc) : "v"(a), "v"(w));
}
// packed f32 FMA, broadcast HI half of w: acc += a * {w.y, w.y}
__device__ inline void pkfma_h(float2& acc, float2 a, float2 w) {
    asm("v_pk_fma_f32 %0, %1, %2, %0 op_sel:[0,1,0] op_sel_hi:[1,1,1]"
        : "+v"(acc) : "v"(a), "v"(w));
}

// FF is a compile-time constant after unrolling -> folds to one pkfma_l/_h
#define WFMA(ACC, XP, FF)                                              \
    do { if (((FF) & 1) == 0) pkfma_l(ACC, XP, wgt[(FF) >> 1]);        \
         else                 pkfma_h(ACC, XP, wgt[(FF) >> 1]); } while (0)
#define WSC(FF) (((FF) & 1) ? wgt[(FF) >> 1].y : wgt[(FF) >> 1].x)

// ---------------- Pass 1: conv + batch stats (+ pooled bf16 max/min store) ----------------
// 256-thread block = 4 independent waves (no LDS, no barrier).
// Wave handles one c-pair; lane t: img=t>>5, o=(t>>4)&1, p=t&15, pi=p>>1, pjp=p&1.
// Lane computes conv rows 2pi..2pi+1 x cols 8pjp..8pjp+7 (4 pooled cells) for its o,
// reading its 4x12 window directly from global (L1/L2-served, immediate offsets).
// Border folded in: col-16 outputs on pjp==1 lanes; row-16 outputs on pi==7 lanes.
template<bool STORE>
__global__ __launch_bounds__(256, 4) void pass1_kernel(
    const float* __restrict__ x1, const float* __restrict__ x2,
    const float* __restrict__ conv_w, const float* __restrict__ conv_b,
    float* __restrict__ ws)
{
    int tt  = threadIdx.x;
    int wv  = tt >> 6;
    int t   = tt & 63;
    int blk = blockIdx.x;            // BATCH * 8
    int b   = blk >> 3;

    int img = t >> 5;
    int u   = t & 31;
    int o   = u >> 4;
    int p   = u & 15;
    int pi  = p >> 1;
    int pjp = p & 1;
    int cpair = (blk & 7) * 4 + wv;
    int c   = cpair * 2 + img;

    size_t ibase = (size_t)(b * 64 + c) * 361;
    int wb = 2 * pi * 19 + 8 * pjp;          // window base (word) within image
    const float* p1 = x1 + ibase + wb;
    const float* p2 = x2 + ibase + wb;

    // weights: natural packed layout (9 x float2), op_sel broadcasts halves
    const float2* wp2 = (const float2*)(conv_w + (size_t)(c * 2 + o) * 18);
    float2 wgt[9];
    #pragma unroll
    for (int j = 0; j < 9; j++) wgt[j] = wp2[j];
    float cbv = conv_b[c * 2 + o];

    // A[di][k]: conv outputs {row 2pi+di, cols 8pjp+2k, 8pjp+2k+1}
    float2 A[2][4];
    #pragma unroll
    for (int di = 0; di < 2; di++)
        #pragma unroll
        for (int k = 0; k < 4; k++)
            A[di][k] = make_float2(cbv, cbv);
    float y16[2] = { cbv, cbv };             // col-16 outputs rows 2pi,2pi+1 (pjp==1)

    #pragma unroll
    for (int ic = 0; ic < 2; ic++) {
        const float* src = ic ? p2 : p1;
        #pragma unroll
        for (int r = 0; r < 4; r++) {
            const float* row = src + 19 * r;
            f4v a4 = *(const f4v*)(row);       // local cols 0..3
            f4v b4 = *(const f4v*)(row + 4);   // 4..7
            f4v c4 = *(const f4v*)(row + 8);   // 8..11 (col overread stays in-image)
            float2 P[9];
            P[0] = make_float2(a4.x, a4.y);
            P[1] = make_float2(a4.y, a4.z);
            P[2] = make_float2(a4.z, a4.w);
            P[3] = make_float2(a4.w, b4.x);
            P[4] = make_float2(b4.x, b4.y);
            P[5] = make_float2(b4.y, b4.z);
            P[6] = make_float2(b4.z, b4.w);
            P[7] = make_float2(b4.w, c4.x);
            P[8] = make_float2(c4.x, c4.y);
            #pragma unroll
            for (int di = 0; di < 2; di++) {
                const int ki = r - di;
                if (ki < 0 || ki > 2) continue;
                #pragma unroll
                for (int k = 0; k < 4; k++)
                    #pragma unroll
                    for (int kj = 0; kj < 3; kj++) {
                        const int ff = ic * 9 + ki * 3 + kj;
                        WFMA(A[di][k], P[2 * k + kj], ff);
                    }
                // col-16 (pjp==1 lanes): local cols 8,9,10 = c4.x,c4.y,c4.z
                {
                    const int f0 = ic * 9 + ki * 3;
                    y16[di] = fmaf(c4.x, WSC(f0 + 0), y16[di]);
                    y16[di] = fmaf(c4.y, WSC(f0 + 1), y16[di]);
                    y16[di] = fmaf(c4.z, WSC(f0 + 2), y16[di]);
                }
            }
        }
    }

    // ---- stats: 16 main outputs ----
    const float2 one2 = make_float2(1.f, 1.f);
    float2 sp = make_float2(0.f, 0.f), sq = make_float2(0.f, 0.f);
    #pragma unroll
    for (int di = 0; di < 2; di++)
        #pragma unroll
        for (int k = 0; k < 4; k++) {
            pkfma(sp, A[di][k], one2);
            pkfma(sq, A[di][k], A[di][k]);
        }
    float s = sp.x + sp.y;
    float q = sq.x + sq.y;

    if (pjp == 1) {                          // col-16 contributions (rows 0..15)
        s += y16[0] + y16[1];
        q = fmaf(y16[0], y16[0], fmaf(y16[1], y16[1], q));
    }

    // ---- row-16 outputs (stats only), pi==7 lanes: (16, 8pjp+0..7) (+ (16,16) on pjp==1) ----
    if (pi == 7) {
        float2 Y[4];
        #pragma unroll
        for (int j = 0; j < 4; j++) Y[j] = make_float2(cbv, cbv);
        float yc = cbv;                      // (16,16), pjp==1 only
        #pragma unroll
        for (int ic = 0; ic < 2; ic++) {
            const float* src = ic ? p2 : p1; // src is at row 14; row16 = +38
            #pragma unroll
            for (int ki = 0; ki < 3; ki++) {
                const float* row = src + 38 + 19 * ki;
                float xx[11];
                if (ki < 2) {
                    f4v a4 = *(const f4v*)(row);
                    f4v b4 = *(const f4v*)(row + 4);
                    f4v c4 = *(const f4v*)(row + 8);
                    xx[0]=a4.x; xx[1]=a4.y; xx[2]=a4.z; xx[3]=a4.w;
                    xx[4]=b4.x; xx[5]=b4.y; xx[6]=b4.z; xx[7]=b4.w;
                    xx[8]=c4.x; xx[9]=c4.y; xx[10]=c4.z;
                } else {                     // row 18: avoid overread at image end
                    f4v a4 = *(const f4v*)(row);
                    f4v b4 = *(const f4v*)(row + 4);
                    f2v d2 = *(const f2v*)(row + 8);
                    float e1 = row[10];
                    xx[0]=a4.x; xx[1]=a4.y; xx[2]=a4.z; xx[3]=a4.w;
                    xx[4]=b4.x; xx[5]=b4.y; xx[6]=b4.z; xx[7]=b4.w;
                    xx[8]=d2.x; xx[9]=d2.y; xx[10]=e1;
                }
                #pragma unroll
                for (int j = 0; j < 4; j++)
                    #pragma unroll
                    for (int kj = 0; kj < 3; kj++) {
                        const int ff = ic * 9 + ki * 3 + kj;
                        float2 xp = make_float2(xx[2 * j + kj], xx[2 * j + kj + 1]);
                        WFMA(Y[j], xp, ff);
                    }
                {
                    const int f0 = ic * 9 + ki * 3;
                    yc = fmaf(xx[8],  WSC(f0 + 0), yc);
                    yc = fmaf(xx[9],  WSC(f0 + 1), yc);
                    yc = fmaf(xx[10], WSC(f0 + 2), yc);
                }
            }
        }
        float2 sp2 = make_float2(0.f, 0.f), sq2 = make_float2(0.f, 0.f);
        #pragma unroll
        for (int j = 0; j < 4; j++) {
            pkfma(sp2, Y[j], one2);
            pkfma(sq2, Y[j], Y[j]);
        }
        float se = sp2.x + sp2.y;
        float qe = sq2.x + sq2.y;
        if (pjp == 1) { se += yc; qe = fmaf(yc, yc, qe); }
        s += se; q += qe;
    }

    // ---- pooled bf16 max/min store ----
    if (STORE) {
        unsigned pk[4];
        #pragma unroll
        for (int k = 0; k < 4; k++) {
            float mx = fmaxf(fmaxf(A[0][k].x, A[0][k].y), fmaxf(A[1][k].x, A[1][k].y));
            float mn = fminf(fminf(A[0][k].x, A[0][k].y), fminf(A[1][k].x, A[1][k].y));
            pk[k] = (bf16rne(mx) << 16) | bf16rne(mn);
        }
        uint4* pool4 = (uint4*)(ws + WS_POOL);
        pool4[((size_t)(b * 64 + c)) * 32 + o * 16 + pi * 2 + pjp] =
            make_uint4(pk[0], pk[1], pk[2], pk[3]);
    }

    // ---- reduce within each 16-lane (img,o) group + atomics ----
    #pragma unroll
    for (int off = 8; off > 0; off >>= 1) {
        s += __shfl_down(s, off, 16);
        q += __shfl_down(q, off, 16);
    }
    if (p == 0) {
        int rep = b & 31;
        atomicAdd(&ws[WS_SUMR + rep * 128 + c * 2 + o], s);
        atomicAdd(&ws[WS_SQR  + rep * 128 + c * 2 + o], q);
    }
}

// ---------------- Prep: replica-sum stats, BN scale/shift, folded fc weights ----------------
__global__ __launch_bounds__(128) void prep_kernel(
    const float* __restrict__ bn_g, const float* __restrict__ bn_b,
    const float* __restrict__ fc1_w, const float* __restrict__ fc1_b,
    const float* __restrict__ fc2_w, const float* __restrict__ fc2_b,
    const float* __restrict__ w_out,
    float* __restrict__ ws)
{
    int c = blockIdx.x;
    int f = threadIdx.x;

    float wsum = 0.f;
    #pragma unroll
    for (int h = 0; h < 8; h++)
        wsum += fc2_w[c * 8 + h] * fc1_w[(c * 8 + h) * 128 + f];
    ws[WS_WF + c * 128 + f] = w_out[c] * wsum;

    if (f == 0) {
        float bsum = fc2_b[c];
        #pragma unroll
        for (int h = 0; h < 8; h++)
            bsum += fc2_w[c * 8 + h] * fc1_b[c * 8 + h];
        ws[WS_WB + c] = w_out[c] * bsum;
    }
    if (f < 2) {
        int idx = c * 2 + f;
        float s = 0.f, q = 0.f;
        for (int r = 0; r < 32; r++) {
            s += ws[WS_SUMR + r * 128 + idx];
            q += ws[WS_SQR  + r * 128 + idx];
        }
        const float N = 2048.0f * 289.0f;
        float mean = s / N;
        float var  = q / N - mean * mean;
        float inv  = rsqrtf(var + EPS);
        float A    = bn_g[idx] * inv;
        ws[WS_A + idx] = A;
        ws[WS_B + idx] = bn_b[idx] - mean * A;
    }
}

// ---------------- Pass 2: stream bf16 pool -> logits -> sigmoid ----------------
__global__ __launch_bounds__(256) void pass2_kernel(
    const float* __restrict__ ws, const float* __restrict__ b_out,
    float* __restrict__ out)
{
    __shared__ float red[4];
    int b = blockIdx.x;
    int t = threadIdx.x;
    const uint4* pool = (const uint4*)(ws + WS_POOL) + (size_t)b * 2048;

    float partial = (t < 64) ? ws[WS_WB + t] : 0.f;
    if (t == 0) partial += b_out[0];

    #pragma unroll
    for (int i = 0; i < 8; i++) {
        uint4 p = pool[t + i * 256];
        int k0 = (t + i * 256) * 4;
        float A  = ws[WS_A + (k0 >> 6)];
        float Bs = ws[WS_B + (k0 >> 6)];
        const float4 wf = *(const float4*)&ws[WS_WF + k0];
        unsigned uu[4] = { p.x, p.y, p.z, p.w };
        float wfv[4] = { wf.x, wf.y, wf.z, wf.w };
        #pragma unroll
        for (int j = 0; j < 4; j++) {
            float mx = __uint_as_float(uu[j] & 0xffff0000u);
            float mn = __uint_as_float(uu[j] << 16);
            float val = A > 0.f ? mx : mn;
            float v = fmaf(A, val, Bs);
            v = v > 0.f ? v : SLOPE * v;
            partial = fmaf(v, wfv[j], partial);
        }
    }

    #pragma unroll
    for (int off = 32; off > 0; off >>= 1)
        partial += __shfl_down(partial, off);
    if ((t & 63) == 0) red[t >> 6] = partial;
    __syncthreads();
    if (t == 0) {
        float lsum = red[0] + red[1] + red[2] + red[3];
        out[b] = 1.f / (1.f + expf(-lsum));
    }
}

// ---------------- Fallback path (small ws): recompute conv with BN applied ----------------
__global__ __launch_bounds__(128) void main_fb_kernel(
    const float* __restrict__ x1, const float* __restrict__ x2,
    const float* __restrict__ conv_w, const float* __restrict__ conv_b,
    float* __restrict__ ws)
{
    __shared__ float lds[2][19 * 20];
    __shared__ float red[2];

    int blk = blockIdx.x;
    int c = blk & 63;
    int b = blk >> 6;
    int t = threadIdx.x;

    const float* src1 = x1 + (size_t)blk * 361;
    const float* src2 = x2 + (size_t)blk * 361;
    for (int i = t; i < 361; i += 128) {
        int r = i / 19;
        int col = i - r * 19;
        lds[0][r * 20 + col] = src1[i];
        lds[1][r * 20 + col] = src2[i];
    }

    int o = t >> 6;
    int l = t & 63;
    int pi = l >> 3, pj = l & 7;

    const float* wcp = conv_w + c * 36 + o * 18;
    float w0[9], w1[9];
    #pragma unroll
    for (int k = 0; k < 9; k++) { w0[k] = wcp[k]; w1[k] = wcp[9 + k]; }
    float cbv = conv_b[c * 2 + o];
    float A   = ws[WS_A + c * 2 + o];
    float Bs  = ws[WS_B + c * 2 + o];
    float wf  = ws[WS_WF + c * 128 + t];

    __syncthreads();

    float xw[2][4][4];
    int base = (2 * pi) * 20 + 2 * pj;
    #pragma unroll
    for (int ic = 0; ic < 2; ic++)
        #pragma unroll
        for (int r = 0; r < 4; r++)
            #pragma unroll
            for (int cc = 0; cc < 4; cc++)
                xw[ic][r][cc] = lds[ic][base + r * 20 + cc];

    float m = -3.4e38f;
    #pragma unroll
    for (int di = 0; di < 2; di++)
        #pragma unroll
        for (int dj = 0; dj < 2; dj++) {
            float acc = cbv;
            #pragma unroll
            for (int ki = 0; ki < 3; ki++)
                #pragma unroll
                for (int kj = 0; kj < 3; kj++) {
                    acc = fmaf(xw[0][di + ki][dj + kj], w0[ki * 3 + kj], acc);
                    acc = fmaf(xw[1][di + ki][dj + kj], w1[ki * 3 + kj], acc);
                }
            float v = fmaf(A, acc, Bs);
            v = v > 0.f ? v : SLOPE * v;
            m = fmaxf(m, v);
        }

    float contrib = m * wf;
    #pragma unroll
    for (int off = 32; off > 0; off >>= 1)
        contrib += __shfl_down(contrib, off);
    if (l == 0) red[o] = contrib;
    __syncthreads();
    if (t == 0)
        atomicAdd(&ws[WS_LOGIT + b], red[0] + red[1]);
}

__global__ __launch_bounds__(256) void final_fb_kernel(
    const float* __restrict__ ws, const float* __restrict__ b_out,
    float* __restrict__ out)
{
    int b = blockIdx.x * blockDim.x + threadIdx.x;
    if (b >= BATCH) return;
    float bias = b_out[0];
    #pragma unroll
    for (int c = 0; c < CC; c++) bias += ws[WS_WB + c];
    float l = ws[WS_LOGIT + b] + bias;
    out[b] = 1.f / (1.f + expf(-l));
}

extern "C" void kernel_launch(void* const* d_in, const int* in_sizes, int n_in,
                              void* d_out, int out_size, void* d_ws, size_t ws_size,
                              hipStream_t stream) {
    const float* x1     = (const float*)d_in[0];
    const float* x2     = (const float*)d_in[1];
    const float* conv_w = (const float*)d_in[2];
    const float* conv_b = (const float*)d_in[3];
    const float* bn_g   = (const float*)d_in[4];
    const float* bn_b   = (const float*)d_in[5];
    const float* fc1_w  = (const float*)d_in[6];
    const float* fc1_b  = (const float*)d_in[7];
    const float* fc2_w  = (const float*)d_in[8];
    const float* fc2_b  = (const float*)d_in[9];
    const float* w_out  = (const float*)d_in[10];
    const float* b_out  = (const float*)d_in[11];
    float* ws  = (float*)d_ws;
    float* out = (float*)d_out;

    bool pool_path = ws_size >= WS_NEEDED_BYTES;

    if (pool_path) {
        hipMemsetAsync(d_ws, 0, 8192 * sizeof(float), stream);   // stats replicas
        pass1_kernel<true><<<dim3(BATCH * 8), 256, 0, stream>>>(x1, x2, conv_w, conv_b, ws);
        prep_kernel<<<CC, 128, 0, stream>>>(bn_g, bn_b, fc1_w, fc1_b, fc2_w, fc2_b, w_out, ws);
        pass2_kernel<<<BATCH, 256, 0, stream>>>(ws, b_out, out);
    } else {
        hipMemsetAsync(d_ws, 0, 18752 * sizeof(float), stream);  // stats + logits
        pass1_kernel<false><<<dim3(BATCH * 8), 256, 0, stream>>>(x1, x2, conv_w, conv_b, ws);
        prep_kernel<<<CC, 128, 0, stream>>>(bn_g, bn_b, fc1_w, fc1_b, fc2_w, fc2_b, w_out, ws);
        main_fb_kernel<<<dim3(BATCH * CC), 128, 0, stream>>>(x1, x2, conv_w, conv_b, ws);
        final_fb_kernel<<<(BATCH + 255) / 256, 256, 0, stream>>>(ws, b_out, out);
    }
}

// Round 14
// 119.692 us; speedup vs baseline: 1.4373x; 1.4373x over previous
//
#include <hip/hip_runtime.h>
#include <math.h>

#define CC    64
#define BATCH 2048
#define EPS   1e-5f
#define SLOPE 0.01f

// ws layout (float indices):
#define WS_SUMR  0        // 32 replicas x 128 (c,o)
#define WS_SQR   4096     // 32 replicas x 128
#define WS_A     8192     // 128
#define WS_B     8320     // 128
#define WS_WF    8448     // 64*128 folded weights
#define WS_WB    16640    // 64 per-channel bias contribution
#define WS_LOGIT 16704    // 2048 (fallback path only)
#define WS_POOL  18944    // 2048*64*128 uint (bf16 mx | bf16 mn), 16B-aligned
#define WS_NEEDED_BYTES ((size_t)(WS_POOL + (size_t)BATCH * CC * 128) * 4)

__device__ inline unsigned bf16rne(float x) {
    unsigned u = __float_as_uint(x);
    return (u + 0x7fffu + ((u >> 16) & 1u)) >> 16;
}

// packed f32 FMA: acc += a*b
__device__ inline void pkfma(float2& acc, float2 a, float2 b) {
    asm("v_pk_fma_f32 %0, %1, %2, %0" : "+v"(acc) : "v"(a), "v"(b));
}
// packed f32 FMA, broadcast LO half of w: acc += a * {w.x, w.x}
__device__ inline void pkfma_l(float2& acc, float2 a, float2 w) {
    asm("v_pk_fma_f32 %0, %1, %2, %0 op_sel:[0,0,0] op_sel_hi:[1,0,1]"
        : "+v"(acc) : "v"(a), "v"(w));
}
// packed f32 FMA, broadcast HI half of w: acc += a * {w.y, w.y}
__device__ inline void pkfma_h(float2& acc, float2 a, float2 w) {
    asm("v_pk_fma_f32 %0, %1, %2, %0 op_sel:[0,1,0] op_sel_hi:[1,1,1]"
        : "+v"(acc) : "v"(a), "v"(w));
}

// FF is a compile-time constant after unrolling -> folds to one pkfma_l/_h
#define WFMA(ACC, XP, FF)                                              \
    do { if (((FF) & 1) == 0) pkfma_l(ACC, XP, wgt[(FF) >> 1]);        \
         else                 pkfma_h(ACC, XP, wgt[(FF) >> 1]); } while (0)
#define WSC(FF) (((FF) & 1) ? wgt[(FF) >> 1].y : wgt[(FF) >> 1].x)

// ---------------- Pass 1: conv + batch stats (+ pooled bf16 max/min store) ----------------
// 128-thread block = 2 waves; wave wv = one c-pair. LDS plane per wave:
// [src][img*380 + row*20 + col] (rows padded 19->20, 16B-aligned window bases).
// Lane t(0..63): img=t>>5, o=(t>>4)&1, p=t&15, pi=p>>1, pjp=p&1.
// Lane: conv rows 2pi..2pi+1 x cols 8pjp..8pjp+7 (4 pooled cells) for its o.
// Border folded in: col-16 on pjp==1 lanes (from regs); row-16 on pi==7 lanes (LDS wide reads).
template<bool STORE>
__global__ __launch_bounds__(128, 4) void pass1_kernel(
    const float* __restrict__ x1, const float* __restrict__ x2,
    const float* __restrict__ conv_w, const float* __restrict__ conv_b,
    float* __restrict__ ws)
{
    __shared__ __align__(16) float lds[2][2][760];

    int blk = blockIdx.x;            // b*16 + cquad
    int tt  = threadIdx.x;
    int wv  = tt >> 6;
    int t   = tt & 63;
    int b     = blk >> 4;
    int cpair = (blk & 15) * 2 + wv;
    int c0    = cpair * 2;

    float (*L)[760] = lds[wv];

    // staging: 361 float2 per source; write idx = e + e/19 (row*20+col)
    const float2* g1 = (const float2*)(x1 + ((size_t)b * 64 + c0) * 361);
    const float2* g2 = (const float2*)(x2 + ((size_t)b * 64 + c0) * 361);
    #pragma unroll
    for (int sl = 0; sl < 6; sl++) {
        int g = t + 64 * sl;
        if (sl < 5 || g < 361) {
            float2 v1 = g1[g];
            float2 v2 = g2[g];
            unsigned e  = 2u * g;
            unsigned r0 = (e * 110377u) >> 21;          // e/19 (exact for e<=721)
            unsigned r1 = ((e + 1u) * 110377u) >> 21;
            int i0 = e + r0;
            int i1 = e + 1 + r1;
            L[0][i0] = v1.x; L[0][i1] = v1.y;
            L[1][i0] = v2.x; L[1][i1] = v2.y;
        }
    }

    int img = t >> 5;
    int u   = t & 31;
    int o   = u >> 4;
    int p   = u & 15;
    int pi  = p >> 1;
    int pjp = p & 1;
    int c   = c0 + img;

    // weights: natural packed layout (9 x float2), op_sel broadcasts halves
    const float2* wp2 = (const float2*)(conv_w + (size_t)(c * 2 + o) * 18);
    float2 wgt[9];
    #pragma unroll
    for (int j = 0; j < 9; j++) wgt[j] = wp2[j];
    float cbv = conv_b[c * 2 + o];

    __syncthreads();

    // A[di][k]: conv outputs {row 2pi+di, cols 8pjp+2k, 8pjp+2k+1}
    float2 A[2][4];
    #pragma unroll
    for (int di = 0; di < 2; di++)
        #pragma unroll
        for (int k = 0; k < 4; k++)
            A[di][k] = make_float2(cbv, cbv);
    float y16[2] = { cbv, cbv };     // col-16 outputs rows 2pi,2pi+1 (valid on pjp==1)

    int wb = img * 380 + pi * 40 + pjp * 8;   // window base (16B aligned)

    #pragma unroll
    for (int ic = 0; ic < 2; ic++) {
        const float* plane = &L[ic][wb];
        #pragma unroll
        for (int r = 0; r < 4; r++) {
            const float* row = plane + 20 * r;
            float4 a4 = *(const float4*)(row);       // local 0..3
            float4 b4 = *(const float4*)(row + 4);   // 4..7
            float4 c4 = *(const float4*)(row + 8);   // 8..11 (<=19 incl pad, in-plane)
            float2 P[9];
            P[0] = make_float2(a4.x, a4.y);
            P[1] = make_float2(a4.y, a4.z);
            P[2] = make_float2(a4.z, a4.w);
            P[3] = make_float2(a4.w, b4.x);
            P[4] = make_float2(b4.x, b4.y);
            P[5] = make_float2(b4.y, b4.z);
            P[6] = make_float2(b4.z, b4.w);
            P[7] = make_float2(b4.w, c4.x);
            P[8] = make_float2(c4.x, c4.y);
            #pragma unroll
            for (int di = 0; di < 2; di++) {
                const int ki = r - di;
                if (ki < 0 || ki > 2) continue;
                #pragma unroll
                for (int k = 0; k < 4; k++)
                    #pragma unroll
                    for (int kj = 0; kj < 3; kj++) {
                        const int ff = ic * 9 + ki * 3 + kj;
                        WFMA(A[di][k], P[2 * k + kj], ff);
                    }
                // col-16 fold (pjp==1): local cols 8,9,10 = global 16,17,18
                {
                    const int f0 = ic * 9 + ki * 3;
                    y16[di] = fmaf(c4.x, WSC(f0 + 0), y16[di]);
                    y16[di] = fmaf(c4.y, WSC(f0 + 1), y16[di]);
                    y16[di] = fmaf(c4.z, WSC(f0 + 2), y16[di]);
                }
            }
        }
    }

    // ---- stats: 16 main outputs ----
    const float2 one2 = make_float2(1.f, 1.f);
    float2 sp = make_float2(0.f, 0.f), sq = make_float2(0.f, 0.f);
    #pragma unroll
    for (int di = 0; di < 2; di++)
        #pragma unroll
        for (int k = 0; k < 4; k++) {
            pkfma(sp, A[di][k], one2);
            pkfma(sq, A[di][k], A[di][k]);
        }
    float s = sp.x + sp.y;
    float q = sq.x + sq.y;

    if (pjp == 1) {                  // col-16 contributions (rows 2pi,2pi+1)
        s += y16[0] + y16[1];
        q = fmaf(y16[0], y16[0], fmaf(y16[1], y16[1], q));
    }

    // ---- row-16 outputs (stats only), pi==7 lanes ----
    if (pi == 7) {
        float2 Y[4];
        #pragma unroll
        for (int j = 0; j < 4; j++) Y[j] = make_float2(cbv, cbv);
        float yc = cbv;              // (16,16), pjp==1 only
        #pragma unroll
        for (int ic = 0; ic < 2; ic++) {
            #pragma unroll
            for (int ki = 0; ki < 3; ki++) {
                const float* row = &L[ic][img * 380 + (16 + ki) * 20 + pjp * 8];
                float4 a4 = *(const float4*)(row);
                float4 b4 = *(const float4*)(row + 4);
                float4 c4 = *(const float4*)(row + 8);
                float2 P[9];
                P[0] = make_float2(a4.x, a4.y);
                P[1] = make_float2(a4.y, a4.z);
                P[2] = make_float2(a4.z, a4.w);
                P[3] = make_float2(a4.w, b4.x);
                P[4] = make_float2(b4.x, b4.y);
                P[5] = make_float2(b4.y, b4.z);
                P[6] = make_float2(b4.z, b4.w);
                P[7] = make_float2(b4.w, c4.x);
                P[8] = make_float2(c4.x, c4.y);
                #pragma unroll
                for (int j = 0; j < 4; j++)
                    #pragma unroll
                    for (int kj = 0; kj < 3; kj++) {
                        const int ff = ic * 9 + ki * 3 + kj;
                        WFMA(Y[j], P[2 * j + kj], ff);
                    }
                {
                    const int f0 = ic * 9 + ki * 3;
                    yc = fmaf(c4.x, WSC(f0 + 0), yc);
                    yc = fmaf(c4.y, WSC(f0 + 1), yc);
                    yc = fmaf(c4.z, WSC(f0 + 2), yc);
                }
            }
        }
        float2 sp2 = make_float2(0.f, 0.f), sq2 = make_float2(0.f, 0.f);
        #pragma unroll
        for (int j = 0; j < 4; j++) {
            pkfma(sp2, Y[j], one2);
            pkfma(sq2, Y[j], Y[j]);
        }
        float se = sp2.x + sp2.y;
        float qe = sq2.x + sq2.y;
        if (pjp == 1) { se += yc; qe = fmaf(yc, yc, qe); }
        s += se; q += qe;
    }

    // ---- pooled bf16 max/min store ----
    if (STORE) {
        unsigned pk[4];
        #pragma unroll
        for (int k = 0; k < 4; k++) {
            float mx = fmaxf(fmaxf(A[0][k].x, A[0][k].y), fmaxf(A[1][k].x, A[1][k].y));
            float mn = fminf(fminf(A[0][k].x, A[0][k].y), fminf(A[1][k].x, A[1][k].y));
            pk[k] = (bf16rne(mx) << 16) | bf16rne(mn);
        }
        uint4* pool4 = (uint4*)(ws + WS_POOL);
        pool4[((size_t)(b * 64 + c)) * 32 + o * 16 + pi * 2 + pjp] =
            make_uint4(pk[0], pk[1], pk[2], pk[3]);
    }

    // ---- reduce within each 16-lane (img,o) group + atomics ----
    #pragma unroll
    for (int off = 8; off > 0; off >>= 1) {
        s += __shfl_down(s, off, 16);
        q += __shfl_down(q, off, 16);
    }
    if (p == 0) {
        int rep = b & 31;
        atomicAdd(&ws[WS_SUMR + rep * 128 + c * 2 + o], s);
        atomicAdd(&ws[WS_SQR  + rep * 128 + c * 2 + o], q);
    }
}

// ---------------- Prep: replica-sum stats, BN scale/shift, folded fc weights ----------------
__global__ __launch_bounds__(128) void prep_kernel(
    const float* __restrict__ bn_g, const float* __restrict__ bn_b,
    const float* __restrict__ fc1_w, const float* __restrict__ fc1_b,
    const float* __restrict__ fc2_w, const float* __restrict__ fc2_b,
    const float* __restrict__ w_out,
    float* __restrict__ ws)
{
    int c = blockIdx.x;
    int f = threadIdx.x;

    float wsum = 0.f;
    #pragma unroll
    for (int h = 0; h < 8; h++)
        wsum += fc2_w[c * 8 + h] * fc1_w[(c * 8 + h) * 128 + f];
    ws[WS_WF + c * 128 + f] = w_out[c] * wsum;

    if (f == 0) {
        float bsum = fc2_b[c];
        #pragma unroll
        for (int h = 0; h < 8; h++)
            bsum += fc2_w[c * 8 + h] * fc1_b[c * 8 + h];
        ws[WS_WB + c] = w_out[c] * bsum;
    }
    if (f < 2) {
        int idx = c * 2 + f;
        float s = 0.f, q = 0.f;
        for (int r = 0; r < 32; r++) {
            s += ws[WS_SUMR + r * 128 + idx];
            q += ws[WS_SQR  + r * 128 + idx];
        }
        const float N = 2048.0f * 289.0f;
        float mean = s / N;
        float var  = q / N - mean * mean;
        float inv  = rsqrtf(var + EPS);
        float A    = bn_g[idx] * inv;
        ws[WS_A + idx] = A;
        ws[WS_B + idx] = bn_b[idx] - mean * A;
    }
}

// ---------------- Pass 2: stream bf16 pool -> logits -> sigmoid ----------------
__global__ __launch_bounds__(256) void pass2_kernel(
    const float* __restrict__ ws, const float* __restrict__ b_out,
    float* __restrict__ out)
{
    __shared__ float red[4];
    int b = blockIdx.x;
    int t = threadIdx.x;
    const uint4* pool = (const uint4*)(ws + WS_POOL) + (size_t)b * 2048;

    float partial = (t < 64) ? ws[WS_WB + t] : 0.f;
    if (t == 0) partial += b_out[0];

    #pragma unroll
    for (int i = 0; i < 8; i++) {
        uint4 p = pool[t + i * 256];
        int k0 = (t + i * 256) * 4;
        float A  = ws[WS_A + (k0 >> 6)];
        float Bs = ws[WS_B + (k0 >> 6)];
        const float4 wf = *(const float4*)&ws[WS_WF + k0];
        unsigned uu[4] = { p.x, p.y, p.z, p.w };
        float wfv[4] = { wf.x, wf.y, wf.z, wf.w };
        #pragma unroll
        for (int j = 0; j < 4; j++) {
            float mx = __uint_as_float(uu[j] & 0xffff0000u);
            float mn = __uint_as_float(uu[j] << 16);
            float val = A > 0.f ? mx : mn;
            float v = fmaf(A, val, Bs);
            v = v > 0.f ? v : SLOPE * v;
            partial = fmaf(v, wfv[j], partial);
        }
    }

    #pragma unroll
    for (int off = 32; off > 0; off >>= 1)
        partial += __shfl_down(partial, off);
    if ((t & 63) == 0) red[t >> 6] = partial;
    __syncthreads();
    if (t == 0) {
        float lsum = red[0] + red[1] + red[2] + red[3];
        out[b] = 1.f / (1.f + expf(-lsum));
    }
}

// ---------------- Fallback path (small ws): recompute conv with BN applied ----------------
__global__ __launch_bounds__(128) void main_fb_kernel(
    const float* __restrict__ x1, const float* __restrict__ x2,
    const float* __restrict__ conv_w, const float* __restrict__ conv_b,
    float* __restrict__ ws)
{
    __shared__ float lds[2][19 * 20];
    __shared__ float red[2];

    int blk = blockIdx.x;
    int c = blk & 63;
    int b = blk >> 6;
    int t = threadIdx.x;

    const float* src1 = x1 + (size_t)blk * 361;
    const float* src2 = x2 + (size_t)blk * 361;
    for (int i = t; i < 361; i += 128) {
        int r = i / 19;
        int col = i - r * 19;
        lds[0][r * 20 + col] = src1[i];
        lds[1][r * 20 + col] = src2[i];
    }

    int o = t >> 6;
    int l = t & 63;
    int pi = l >> 3, pj = l & 7;

    const float* wcp = conv_w + c * 36 + o * 18;
    float w0[9], w1[9];
    #pragma unroll
    for (int k = 0; k < 9; k++) { w0[k] = wcp[k]; w1[k] = wcp[9 + k]; }
    float cbv = conv_b[c * 2 + o];
    float A   = ws[WS_A + c * 2 + o];
    float Bs  = ws[WS_B + c * 2 + o];
    float wf  = ws[WS_WF + c * 128 + t];

    __syncthreads();

    float xw[2][4][4];
    int base = (2 * pi) * 20 + 2 * pj;
    #pragma unroll
    for (int ic = 0; ic < 2; ic++)
        #pragma unroll
        for (int r = 0; r < 4; r++)
            #pragma unroll
            for (int cc = 0; cc < 4; cc++)
                xw[ic][r][cc] = lds[ic][base + r * 20 + cc];

    float m = -3.4e38f;
    #pragma unroll
    for (int di = 0; di < 2; di++)
        #pragma unroll
        for (int dj = 0; dj < 2; dj++) {
            float acc = cbv;
            #pragma unroll
            for (int ki = 0; ki < 3; ki++)
                #pragma unroll
                for (int kj = 0; kj < 3; kj++) {
                    acc = fmaf(xw[0][di + ki][dj + kj], w0[ki * 3 + kj], acc);
                    acc = fmaf(xw[1][di + ki][dj + kj], w1[ki * 3 + kj], acc);
                }
            float v = fmaf(A, acc, Bs);
            v = v > 0.f ? v : SLOPE * v;
            m = fmaxf(m, v);
        }

    float contrib = m * wf;
    #pragma unroll
    for (int off = 32; off > 0; off >>= 1)
        contrib += __shfl_down(contrib, off);
    if (l == 0) red[o] = contrib;
    __syncthreads();
    if (t == 0)
        atomicAdd(&ws[WS_LOGIT + b], red[0] + red[1]);
}

__global__ __launch_bounds__(256) void final_fb_kernel(
    const float* __restrict__ ws, const float* __restrict__ b_out,
    float* __restrict__ out)
{
    int b = blockIdx.x * blockDim.x + threadIdx.x;
    if (b >= BATCH) return;
    float bias = b_out[0];
    #pragma unroll
    for (int c = 0; c < CC; c++) bias += ws[WS_WB + c];
    float l = ws[WS_LOGIT + b] + bias;
    out[b] = 1.f / (1.f + expf(-l));
}

extern "C" void kernel_launch(void* const* d_in, const int* in_sizes, int n_in,
                              void* d_out, int out_size, void* d_ws, size_t ws_size,
                              hipStream_t stream) {
    const float* x1     = (const float*)d_in[0];
    const float* x2     = (const float*)d_in[1];
    const float* conv_w = (const float*)d_in[2];
    const float* conv_b = (const float*)d_in[3];
    const float* bn_g   = (const float*)d_in[4];
    const float* bn_b   = (const float*)d_in[5];
    const float* fc1_w  = (const float*)d_in[6];
    const float* fc1_b  = (const float*)d_in[7];
    const float* fc2_w  = (const float*)d_in[8];
    const float* fc2_b  = (const float*)d_in[9];
    const float* w_out  = (const float*)d_in[10];
    const float* b_out  = (const float*)d_in[11];
    float* ws  = (float*)d_ws;
    float* out = (float*)d_out;

    dim3 big(BATCH * 16);            // 128 threads = 2 waves = 2 c-pairs per block
    bool pool_path = ws_size >= WS_NEEDED_BYTES;

    if (pool_path) {
        hipMemsetAsync(d_ws, 0, 8192 * sizeof(float), stream);   // stats replicas
        pass1_kernel<true><<<big, 128, 0, stream>>>(x1, x2, conv_w, conv_b, ws);
        prep_kernel<<<CC, 128, 0, stream>>>(bn_g, bn_b, fc1_w, fc1_b, fc2_w, fc2_b, w_out, ws);
        pass2_kernel<<<BATCH, 256, 0, stream>>>(ws, b_out, out);
    } else {
        hipMemsetAsync(d_ws, 0, 18752 * sizeof(float), stream);  // stats + logits
        pass1_kernel<false><<<big, 128, 0, stream>>>(x1, x2, conv_w, conv_b, ws);
        prep_kernel<<<CC, 128, 0, stream>>>(bn_g, bn_b, fc1_w, fc1_b, fc2_w, fc2_b, w_out, ws);
        main_fb_kernel<<<dim3(BATCH * CC), 128, 0, stream>>>(x1, x2, conv_w, conv_b, ws);
        final_fb_kernel<<<(BATCH + 255) / 256, 256, 0, stream>>>(ws, b_out, out);
    }
}

// Round 15
// 115.800 us; speedup vs baseline: 1.4856x; 1.0336x over previous
//
#include <hip/hip_runtime.h>
#include <math.h>

#define CC    64
#define BATCH 2048
#define EPS   1e-5f
#define SLOPE 0.01f

// ws layout (float indices):
#define WS_SUMR  0        // 32 replicas x 128 (c,o)
#define WS_SQR   4096     // 32 replicas x 128
#define WS_A     8192     // 128
#define WS_B     8320     // 128
#define WS_WF    8448     // 64*128 folded weights
#define WS_WB    16640    // 64 per-channel bias contribution
#define WS_LOGIT 16704    // 2048 (fallback path only)
#define WS_POOL  18944    // 2048*64*128 uint (bf16 mx | bf16 mn), 16B-aligned
#define WS_NEEDED_BYTES ((size_t)(WS_POOL + (size_t)BATCH * CC * 128) * 4)

__device__ inline unsigned bf16rne(float x) {
    unsigned u = __float_as_uint(x);
    return (u + 0x7fffu + ((u >> 16) & 1u)) >> 16;
}

// packed f32 FMA: acc += a*b (both halves natural)
__device__ inline void pkfma(float2& acc, float2 a, float2 b) {
    asm("v_pk_fma_f32 %0, %1, %2, %0" : "+v"(acc) : "v"(a), "v"(b));
}
// acc += {x.lo, x.lo} * w   (broadcast LO half of x to both lanes)
__device__ inline void pk_xl(float2& acc, float2 x, float2 w) {
    asm("v_pk_fma_f32 %0, %1, %2, %0 op_sel:[0,0,0] op_sel_hi:[0,1,1]"
        : "+v"(acc) : "v"(x), "v"(w));
}
// acc += {x.hi, x.hi} * w   (broadcast HI half of x)
__device__ inline void pk_xh(float2& acc, float2 x, float2 w) {
    asm("v_pk_fma_f32 %0, %1, %2, %0 op_sel:[1,0,0] op_sel_hi:[1,1,1]"
        : "+v"(acc) : "v"(x), "v"(w));
}

// ---------------- Pass 1: conv + batch stats (+ pooled bf16 max/min store) ----------------
// 128-thread block = 2 waves; wave wv = one c-pair. LDS plane per wave:
// [src][img*380 + row*20 + col] (rows padded 19->20).
// Lane t(0..63): img=t>>5, p=t&31, pi=p>>2 (pool row), h=p&3.
// Lane computes BOTH o channels (packed in float2 accumulators via op_sel broadcast)
// for 2 pool cells (pi,2h),(pi,2h+1): conv rows 2pi..2pi+1, cols 4h..4h+3.
// Border: one position per lane (scalar), + (15,16) on lane p==0.
template<bool STORE>
__global__ __launch_bounds__(128, 4) void pass1_kernel(
    const float* __restrict__ x1, const float* __restrict__ x2,
    const float* __restrict__ conv_w, const float* __restrict__ conv_b,
    float* __restrict__ ws)
{
    __shared__ __align__(16) float lds[2][2][760];

    int blk = blockIdx.x;            // b*16 + cquad
    int tt  = threadIdx.x;
    int wv  = tt >> 6;
    int t   = tt & 63;
    int b     = blk >> 4;
    int cpair = (blk & 15) * 2 + wv;
    int c0    = cpair * 2;

    float (*L)[760] = lds[wv];

    // staging: 361 float2 per source; write idx = e + e/19 (row*20+col)
    const float2* g1 = (const float2*)(x1 + ((size_t)b * 64 + c0) * 361);
    const float2* g2 = (const float2*)(x2 + ((size_t)b * 64 + c0) * 361);
    #pragma unroll
    for (int sl = 0; sl < 6; sl++) {
        int g = t + 64 * sl;
        if (sl < 5 || g < 361) {
            float2 v1 = g1[g];
            float2 v2 = g2[g];
            unsigned e  = 2u * g;
            unsigned r0 = (e * 110377u) >> 21;          // e/19 (exact for e<=721)
            unsigned r1 = ((e + 1u) * 110377u) >> 21;
            int i0 = e + r0;
            int i1 = e + 1 + r1;
            L[0][i0] = v1.x; L[0][i1] = v1.y;
            L[1][i0] = v2.x; L[1][i1] = v2.y;
        }
    }

    int img = t >> 5;
    int p   = t & 31;
    int pi  = p >> 2;
    int h   = p & 3;
    int c   = c0 + img;

    // weights interleaved over o: w2[f] = {w_o0[f], w_o1[f]}, f = ic*9+ki*3+kj
    const float2* wpa = (const float2*)(conv_w + (size_t)(c * 2 + 0) * 18);
    const float2* wpb = (const float2*)(conv_w + (size_t)(c * 2 + 1) * 18);
    float2 w2[18];
    #pragma unroll
    for (int j = 0; j < 9; j++) {
        float2 pa = wpa[j], pb = wpb[j];
        w2[2 * j]     = make_float2(pa.x, pb.x);
        w2[2 * j + 1] = make_float2(pa.y, pb.y);
    }
    float2 cb2 = *(const float2*)(conv_b + c * 2);   // {cb_o0, cb_o1}

    __syncthreads();

    // A2[di][j] = {y_o0, y_o1} at conv (row 2pi+di, col 4h+j), j=0..3
    float2 A2[2][4];
    #pragma unroll
    for (int di = 0; di < 2; di++)
        #pragma unroll
        for (int j = 0; j < 4; j++)
            A2[di][j] = cb2;

    int wb = img * 380 + pi * 40 + h * 4;     // window base (16B aligned)

    #pragma unroll
    for (int ic = 0; ic < 2; ic++) {
        const float* plane = &L[ic][wb];
        #pragma unroll
        for (int r = 0; r < 4; r++) {
            const float* row = plane + 20 * r;
            float4 a4 = *(const float4*)row;          // x0..x3
            float2 d2 = *(const float2*)(row + 4);    // x4,x5
            float2 PA = make_float2(a4.x, a4.y);      // natural pairs (no shuffle)
            float2 PB = make_float2(a4.z, a4.w);
            float2 PC = d2;
            #pragma unroll
            for (int di = 0; di < 2; di++) {
                const int ki = r - di;
                if (ki < 0 || ki > 2) continue;
                const int f0 = ic * 9 + ki * 3;
                // col j=0: x0,x1,x2
                pk_xl(A2[di][0], PA, w2[f0 + 0]);
                pk_xh(A2[di][0], PA, w2[f0 + 1]);
                pk_xl(A2[di][0], PB, w2[f0 + 2]);
                // col j=1: x1,x2,x3
                pk_xh(A2[di][1], PA, w2[f0 + 0]);
                pk_xl(A2[di][1], PB, w2[f0 + 1]);
                pk_xh(A2[di][1], PB, w2[f0 + 2]);
                // col j=2: x2,x3,x4
                pk_xl(A2[di][2], PB, w2[f0 + 0]);
                pk_xh(A2[di][2], PB, w2[f0 + 1]);
                pk_xl(A2[di][2], PC, w2[f0 + 2]);
                // col j=3: x3,x4,x5
                pk_xh(A2[di][3], PB, w2[f0 + 0]);
                pk_xl(A2[di][3], PC, w2[f0 + 1]);
                pk_xh(A2[di][3], PC, w2[f0 + 2]);
            }
        }
    }

    // ---- stats over the 8 packed outputs ----
    const float2 one2 = make_float2(1.f, 1.f);
    float2 sum2 = make_float2(0.f, 0.f), sq2 = make_float2(0.f, 0.f);
    #pragma unroll
    for (int di = 0; di < 2; di++)
        #pragma unroll
        for (int j = 0; j < 4; j++) {
            pkfma(sum2, A2[di][j], one2);
            pkfma(sq2, A2[di][j], A2[di][j]);
        }
    float s0 = sum2.x, s1 = sum2.y, q0 = sq2.x, q1 = sq2.y;

    // ---- border: one position per lane (both o, scalar) ----
    {
        int bi = p < 17 ? 16 : p - 17;    // (16,0..16) then (0..14,16)
        int bj = p < 17 ? p  : 16;
        int bw = img * 380 + bi * 20 + bj;
        float y0 = cb2.x, y1 = cb2.y;
        #pragma unroll
        for (int ic = 0; ic < 2; ic++)
            #pragma unroll
            for (int ki = 0; ki < 3; ki++)
                #pragma unroll
                for (int kj = 0; kj < 3; kj++) {
                    float v = L[ic][bw + 20 * ki + kj];
                    const int ff = ic * 9 + ki * 3 + kj;
                    y0 = fmaf(v, w2[ff].x, y0);
                    y1 = fmaf(v, w2[ff].y, y1);
                }
        s0 += y0; q0 = fmaf(y0, y0, q0);
        s1 += y1; q1 = fmaf(y1, y1, q1);
    }
    if (p == 0) {                        // remaining border position (15,16)
        int bw = img * 380 + 15 * 20 + 16;
        float y0 = cb2.x, y1 = cb2.y;
        #pragma unroll
        for (int ic = 0; ic < 2; ic++)
            #pragma unroll
            for (int ki = 0; ki < 3; ki++)
                #pragma unroll
                for (int kj = 0; kj < 3; kj++) {
                    float v = L[ic][bw + 20 * ki + kj];
                    const int ff = ic * 9 + ki * 3 + kj;
                    y0 = fmaf(v, w2[ff].x, y0);
                    y1 = fmaf(v, w2[ff].y, y1);
                }
        s0 += y0; q0 = fmaf(y0, y0, q0);
        s1 += y1; q1 = fmaf(y1, y1, q1);
    }

    // ---- pooled bf16 max/min store: cells (pi,2h) [j=0,1] and (pi,2h+1) [j=2,3] ----
    if (STORE) {
        float mxA0 = fmaxf(fmaxf(A2[0][0].x, A2[0][1].x), fmaxf(A2[1][0].x, A2[1][1].x));
        float mnA0 = fminf(fminf(A2[0][0].x, A2[0][1].x), fminf(A2[1][0].x, A2[1][1].x));
        float mxB0 = fmaxf(fmaxf(A2[0][2].x, A2[0][3].x), fmaxf(A2[1][2].x, A2[1][3].x));
        float mnB0 = fminf(fminf(A2[0][2].x, A2[0][3].x), fminf(A2[1][2].x, A2[1][3].x));
        float mxA1 = fmaxf(fmaxf(A2[0][0].y, A2[0][1].y), fmaxf(A2[1][0].y, A2[1][1].y));
        float mnA1 = fminf(fminf(A2[0][0].y, A2[0][1].y), fminf(A2[1][0].y, A2[1][1].y));
        float mxB1 = fmaxf(fmaxf(A2[0][2].y, A2[0][3].y), fmaxf(A2[1][2].y, A2[1][3].y));
        float mnB1 = fminf(fminf(A2[0][2].y, A2[0][3].y), fminf(A2[1][2].y, A2[1][3].y));
        unsigned* pool = (unsigned*)(ws + WS_POOL);
        size_t base = ((size_t)(b * 64 + c)) * 128;
        int cell = pi * 8 + 2 * h;
        *(uint2*)&pool[base + cell] =
            make_uint2((bf16rne(mxA0) << 16) | bf16rne(mnA0),
                       (bf16rne(mxB0) << 16) | bf16rne(mnB0));
        *(uint2*)&pool[base + 64 + cell] =
            make_uint2((bf16rne(mxA1) << 16) | bf16rne(mnA1),
                       (bf16rne(mxB1) << 16) | bf16rne(mnB1));
    }

    // ---- reduce within 32-lane img group + atomics ----
    #pragma unroll
    for (int off = 16; off > 0; off >>= 1) {
        s0 += __shfl_down(s0, off, 32);
        q0 += __shfl_down(q0, off, 32);
        s1 += __shfl_down(s1, off, 32);
        q1 += __shfl_down(q1, off, 32);
    }
    if (p == 0) {
        int rep = b & 31;
        atomicAdd(&ws[WS_SUMR + rep * 128 + c * 2 + 0], s0);
        atomicAdd(&ws[WS_SQR  + rep * 128 + c * 2 + 0], q0);
        atomicAdd(&ws[WS_SUMR + rep * 128 + c * 2 + 1], s1);
        atomicAdd(&ws[WS_SQR  + rep * 128 + c * 2 + 1], q1);
    }
}

// ---------------- Prep: replica-sum stats, BN scale/shift, folded fc weights ----------------
__global__ __launch_bounds__(128) void prep_kernel(
    const float* __restrict__ bn_g, const float* __restrict__ bn_b,
    const float* __restrict__ fc1_w, const float* __restrict__ fc1_b,
    const float* __restrict__ fc2_w, const float* __restrict__ fc2_b,
    const float* __restrict__ w_out,
    float* __restrict__ ws)
{
    int c = blockIdx.x;
    int f = threadIdx.x;

    float wsum = 0.f;
    #pragma unroll
    for (int h = 0; h < 8; h++)
        wsum += fc2_w[c * 8 + h] * fc1_w[(c * 8 + h) * 128 + f];
    ws[WS_WF + c * 128 + f] = w_out[c] * wsum;

    if (f == 0) {
        float bsum = fc2_b[c];
        #pragma unroll
        for (int h = 0; h < 8; h++)
            bsum += fc2_w[c * 8 + h] * fc1_b[c * 8 + h];
        ws[WS_WB + c] = w_out[c] * bsum;
    }
    if (f < 2) {
        int idx = c * 2 + f;
        float s = 0.f, q = 0.f;
        for (int r = 0; r < 32; r++) {
            s += ws[WS_SUMR + r * 128 + idx];
            q += ws[WS_SQR  + r * 128 + idx];
        }
        const float N = 2048.0f * 289.0f;
        float mean = s / N;
        float var  = q / N - mean * mean;
        float inv  = rsqrtf(var + EPS);
        float A    = bn_g[idx] * inv;
        ws[WS_A + idx] = A;
        ws[WS_B + idx] = bn_b[idx] - mean * A;
    }
}

// ---------------- Pass 2: stream bf16 pool -> logits -> sigmoid ----------------
__global__ __launch_bounds__(256) void pass2_kernel(
    const float* __restrict__ ws, const float* __restrict__ b_out,
    float* __restrict__ out)
{
    __shared__ float red[4];
    int b = blockIdx.x;
    int t = threadIdx.x;
    const uint4* pool = (const uint4*)(ws + WS_POOL) + (size_t)b * 2048;

    float partial = (t < 64) ? ws[WS_WB + t] : 0.f;
    if (t == 0) partial += b_out[0];

    #pragma unroll
    for (int i = 0; i < 8; i++) {
        uint4 p = pool[t + i * 256];
        int k0 = (t + i * 256) * 4;
        float A  = ws[WS_A + (k0 >> 6)];
        float Bs = ws[WS_B + (k0 >> 6)];
        const float4 wf = *(const float4*)&ws[WS_WF + k0];
        unsigned uu[4] = { p.x, p.y, p.z, p.w };
        float wfv[4] = { wf.x, wf.y, wf.z, wf.w };
        #pragma unroll
        for (int j = 0; j < 4; j++) {
            float mx = __uint_as_float(uu[j] & 0xffff0000u);
            float mn = __uint_as_float(uu[j] << 16);
            float val = A > 0.f ? mx : mn;
            float v = fmaf(A, val, Bs);
            v = v > 0.f ? v : SLOPE * v;
            partial = fmaf(v, wfv[j], partial);
        }
    }

    #pragma unroll
    for (int off = 32; off > 0; off >>= 1)
        partial += __shfl_down(partial, off);
    if ((t & 63) == 0) red[t >> 6] = partial;
    __syncthreads();
    if (t == 0) {
        float lsum = red[0] + red[1] + red[2] + red[3];
        out[b] = 1.f / (1.f + expf(-lsum));
    }
}

// ---------------- Fallback path (small ws): recompute conv with BN applied ----------------
__global__ __launch_bounds__(128) void main_fb_kernel(
    const float* __restrict__ x1, const float* __restrict__ x2,
    const float* __restrict__ conv_w, const float* __restrict__ conv_b,
    float* __restrict__ ws)
{
    __shared__ float lds[2][19 * 20];
    __shared__ float red[2];

    int blk = blockIdx.x;
    int c = blk & 63;
    int b = blk >> 6;
    int t = threadIdx.x;

    const float* src1 = x1 + (size_t)blk * 361;
    const float* src2 = x2 + (size_t)blk * 361;
    for (int i = t; i < 361; i += 128) {
        int r = i / 19;
        int col = i - r * 19;
        lds[0][r * 20 + col] = src1[i];
        lds[1][r * 20 + col] = src2[i];
    }

    int o = t >> 6;
    int l = t & 63;
    int pi = l >> 3, pj = l & 7;

    const float* wcp = conv_w + c * 36 + o * 18;
    float w0[9], w1[9];
    #pragma unroll
    for (int k = 0; k < 9; k++) { w0[k] = wcp[k]; w1[k] = wcp[9 + k]; }
    float cbv = conv_b[c * 2 + o];
    float A   = ws[WS_A + c * 2 + o];
    float Bs  = ws[WS_B + c * 2 + o];
    float wf  = ws[WS_WF + c * 128 + t];

    __syncthreads();

    float xw[2][4][4];
    int base = (2 * pi) * 20 + 2 * pj;
    #pragma unroll
    for (int ic = 0; ic < 2; ic++)
        #pragma unroll
        for (int r = 0; r < 4; r++)
            #pragma unroll
            for (int cc = 0; cc < 4; cc++)
                xw[ic][r][cc] = lds[ic][base + r * 20 + cc];

    float m = -3.4e38f;
    #pragma unroll
    for (int di = 0; di < 2; di++)
        #pragma unroll
        for (int dj = 0; dj < 2; dj++) {
            float acc = cbv;
            #pragma unroll
            for (int ki = 0; ki < 3; ki++)
                #pragma unroll
                for (int kj = 0; kj < 3; kj++) {
                    acc = fmaf(xw[0][di + ki][dj + kj], w0[ki * 3 + kj], acc);
                    acc = fmaf(xw[1][di + ki][dj + kj], w1[ki * 3 + kj], acc);
                }
            float v = fmaf(A, acc, Bs);
            v = v > 0.f ? v : SLOPE * v;
            m = fmaxf(m, v);
        }

    float contrib = m * wf;
    #pragma unroll
    for (int off = 32; off > 0; off >>= 1)
        contrib += __shfl_down(contrib, off);
    if (l == 0) red[o] = contrib;
    __syncthreads();
    if (t == 0)
        atomicAdd(&ws[WS_LOGIT + b], red[0] + red[1]);
}

__global__ __launch_bounds__(256) void final_fb_kernel(
    const float* __restrict__ ws, const float* __restrict__ b_out,
    float* __restrict__ out)
{
    int b = blockIdx.x * blockDim.x + threadIdx.x;
    if (b >= BATCH) return;
    float bias = b_out[0];
    #pragma unroll
    for (int c = 0; c < CC; c++) bias += ws[WS_WB + c];
    float l = ws[WS_LOGIT + b] + bias;
    out[b] = 1.f / (1.f + expf(-l));
}

extern "C" void kernel_launch(void* const* d_in, const int* in_sizes, int n_in,
                              void* d_out, int out_size, void* d_ws, size_t ws_size,
                              hipStream_t stream) {
    const float* x1     = (const float*)d_in[0];
    const float* x2     = (const float*)d_in[1];
    const float* conv_w = (const float*)d_in[2];
    const float* conv_b = (const float*)d_in[3];
    const float* bn_g   = (const float*)d_in[4];
    const float* bn_b   = (const float*)d_in[5];
    const float* fc1_w  = (const float*)d_in[6];
    const float* fc1_b  = (const float*)d_in[7];
    const float* fc2_w  = (const float*)d_in[8];
    const float* fc2_b  = (const float*)d_in[9];
    const float* w_out  = (const float*)d_in[10];
    const float* b_out  = (const float*)d_in[11];
    float* ws  = (float*)d_ws;
    float* out = (float*)d_out;

    dim3 big(BATCH * 16);            // 128 threads = 2 waves = 2 c-pairs per block
    bool pool_path = ws_size >= WS_NEEDED_BYTES;

    if (pool_path) {
        hipMemsetAsync(d_ws, 0, 8192 * sizeof(float), stream);   // stats replicas
        pass1_kernel<true><<<big, 128, 0, stream>>>(x1, x2, conv_w, conv_b, ws);
        prep_kernel<<<CC, 128, 0, stream>>>(bn_g, bn_b, fc1_w, fc1_b, fc2_w, fc2_b, w_out, ws);
        pass2_kernel<<<BATCH, 256, 0, stream>>>(ws, b_out, out);
    } else {
        hipMemsetAsync(d_ws, 0, 18752 * sizeof(float), stream);  // stats + logits
        pass1_kernel<false><<<big, 128, 0, stream>>>(x1, x2, conv_w, conv_b, ws);
        prep_kernel<<<CC, 128, 0, stream>>>(bn_g, bn_b, fc1_w, fc1_b, fc2_w, fc2_b, w_out, ws);
        main_fb_kernel<<<dim3(BATCH * CC), 128, 0, stream>>>(x1, x2, conv_w, conv_b, ws);
        final_fb_kernel<<<(BATCH + 255) / 256, 256, 0, stream>>>(ws, b_out, out);
    }
}

// Round 16
// 113.391 us; speedup vs baseline: 1.5172x; 1.0212x over previous
//
#include <hip/hip_runtime.h>
#include <math.h>

#define CC    64
#define BATCH 2048
#define EPS   1e-5f
#define SLOPE 0.01f

// ws layout (float indices):
#define WS_SUMR  0        // 32 replicas x 128 (c,o)
#define WS_SQR   4096     // 32 replicas x 128
#define WS_A     8192     // 128
#define WS_B     8320     // 128
#define WS_WF    8448     // 64*128 folded weights
#define WS_WB    16640    // 64 per-channel bias contribution
#define WS_LOGIT 16704    // 2048 (fallback path only)
#define WS_POOL  18944    // 2048*64*128 uint (bf16 mx | bf16 mn), 16B-aligned
#define WS_NEEDED_BYTES ((size_t)(WS_POOL + (size_t)BATCH * CC * 128) * 4)

__device__ inline unsigned bf16rne(float x) {
    unsigned u = __float_as_uint(x);
    return (u + 0x7fffu + ((u >> 16) & 1u)) >> 16;
}

// guaranteed packed f32 FMA: acc = a*b + acc (VOP3P v_pk_fma_f32, CDNA4)
__device__ inline void pkfma(float2& acc, float2 a, float2 b) {
    asm("v_pk_fma_f32 %0, %1, %2, %0" : "+v"(acc) : "v"(a), "v"(b));
}

// ---------------- Pass 1: conv + batch stats (+ pooled bf16 max/min store) ----------------
// One 64-thread block = one wave = 2 images (b,c0),(b,c0+1).
// LDS: [src][img*380 + row*20 + col]  (rows padded 19->20 so every window base is 16B aligned).
// Lane t: img=t>>5, o=(t>>4)&1, p=t&15, pi=p>>1, pjp=p&1
//   -> 4 pooled cells (pi, 4pjp..4pjp+3): conv rows 2pi..2pi+1, conv cols 8pjp..8pjp+7,
//      input window rows 2pi..2pi+3, cols 8pjp..8pjp+9 (10 words, aligned).
template<bool STORE>
__global__ __launch_bounds__(64, 4) void pass1_kernel(
    const float* __restrict__ x1, const float* __restrict__ x2,
    const float* __restrict__ conv_w, const float* __restrict__ conv_b,
    float* __restrict__ ws)
{
    __shared__ __align__(16) float lds[2][760];

    int blk = blockIdx.x;            // b*32 + cpair
    int b  = blk >> 5;
    int c0 = (blk & 31) * 2;
    int t  = threadIdx.x;            // 0..63

    // staging: 361 float2 per source; write idx = e + e/19 (img pad falls out)
    const float2* g1 = (const float2*)(x1 + ((size_t)b * 64 + c0) * 361);
    const float2* g2 = (const float2*)(x2 + ((size_t)b * 64 + c0) * 361);
    #pragma unroll
    for (int sl = 0; sl < 6; sl++) {
        int g = t + 64 * sl;
        if (sl < 5 || g < 361) {
            float2 v1 = g1[g];
            float2 v2 = g2[g];
            unsigned e  = 2u * g;
            unsigned r0 = (e * 110377u) >> 21;          // e/19 (exact for e<=721)
            unsigned r1 = ((e + 1u) * 110377u) >> 21;
            int i0 = e + r0;
            int i1 = e + 1 + r1;
            lds[0][i0] = v1.x; lds[0][i1] = v1.y;
            lds[1][i0] = v2.x; lds[1][i1] = v2.y;
        }
    }

    int img = t >> 5;
    int u   = t & 31;
    int o   = u >> 4;
    int p   = u & 15;
    int pi  = p >> 1;
    int pjp = p & 1;
    int c   = c0 + img;

    // weights as {w,w} pairs
    const float2* wp2 = (const float2*)(conv_w + (size_t)(c * 2 + o) * 18);
    float2 wgt[18];
    #pragma unroll
    for (int j = 0; j < 9; j++) {
        float2 pr = wp2[j];
        wgt[2 * j]     = make_float2(pr.x, pr.x);
        wgt[2 * j + 1] = make_float2(pr.y, pr.y);
    }
    float cbv = conv_b[c * 2 + o];

    __syncthreads();

    // A[di][k] = conv outputs {row 2pi+di, cols 8pjp+2k, 8pjp+2k+1} (cell k of 4)
    float2 A[2][4];
    #pragma unroll
    for (int di = 0; di < 2; di++)
        #pragma unroll
        for (int k = 0; k < 4; k++)
            A[di][k] = make_float2(cbv, cbv);

    int wb = img * 380 + pi * 40 + pjp * 8;   // window base (mod 4 == 0)

    #pragma unroll
    for (int ic = 0; ic < 2; ic++) {
        const float* plane = &lds[ic][wb];
        const float2* wic = &wgt[ic * 9];
        #pragma unroll
        for (int r = 0; r < 4; r++) {
            const float* row = plane + 20 * r;
            float4 a4 = *(const float4*)(row);       // x0..x3
            float4 b4 = *(const float4*)(row + 4);   // x4..x7
            float2 c2 = *(const float2*)(row + 8);   // x8,x9
            float2 P[9];
            P[0] = make_float2(a4.x, a4.y);
            P[1] = make_float2(a4.y, a4.z);
            P[2] = make_float2(a4.z, a4.w);
            P[3] = make_float2(a4.w, b4.x);
            P[4] = make_float2(b4.x, b4.y);
            P[5] = make_float2(b4.y, b4.z);
            P[6] = make_float2(b4.z, b4.w);
            P[7] = make_float2(b4.w, c2.x);
            P[8] = make_float2(c2.x, c2.y);
            #pragma unroll
            for (int di = 0; di < 2; di++) {
                int ki = r - di;
                if (ki < 0 || ki > 2) continue;
                #pragma unroll
                for (int k = 0; k < 4; k++)
                    #pragma unroll
                    for (int kj = 0; kj < 3; kj++)
                        pkfma(A[di][k], P[2 * k + kj], wic[3 * ki + kj]);
            }
        }
    }

    // stats + pooled max/min (cell k: A[0][k], A[1][k])
    const float2 one2 = make_float2(1.f, 1.f);
    float2 sp = make_float2(0.f, 0.f), q2 = make_float2(0.f, 0.f);
    #pragma unroll
    for (int di = 0; di < 2; di++)
        #pragma unroll
        for (int k = 0; k < 4; k++) {
            pkfma(sp, A[di][k], one2);
            pkfma(q2, A[di][k], A[di][k]);
        }
    float s = sp.x + sp.y;
    float q = q2.x + q2.y;

    if (STORE) {
        unsigned pk[4];
        #pragma unroll
        for (int k = 0; k < 4; k++) {
            float mx = fmaxf(fmaxf(A[0][k].x, A[0][k].y), fmaxf(A[1][k].x, A[1][k].y));
            float mn = fminf(fminf(A[0][k].x, A[0][k].y), fminf(A[1][k].x, A[1][k].y));
            pk[k] = (bf16rne(mx) << 16) | bf16rne(mn);
        }
        uint4* pool4 = (uint4*)(ws + WS_POOL);
        pool4[((size_t)(b * 64 + c)) * 32 + o * 16 + pi * 2 + pjp] =
            make_uint4(pk[0], pk[1], pk[2], pk[3]);
    }

    // border outputs (stats only), 33 per (img,o): (16,0..16) and (0..14,16) via 2 reps, + (15,16)
    int ibase = img * 380;
    #pragma unroll
    for (int rep = 0; rep < 2; rep++) {
        int bidx = p + 16 * rep;
        int bi = bidx < 17 ? 16 : bidx - 17;
        int bj = bidx < 17 ? bidx : 16;
        int bw = ibase + 20 * bi + bj;
        float accb = cbv;
        #pragma unroll
        for (int ic = 0; ic < 2; ic++)
            #pragma unroll
            for (int ki = 0; ki < 3; ki++)
                #pragma unroll
                for (int kj = 0; kj < 3; kj++)
                    accb = fmaf(lds[ic][bw + 20 * ki + kj], wgt[ic * 9 + ki * 3 + kj].x, accb);
        s += accb; q = fmaf(accb, accb, q);
    }
    if (p == 0) {   // (15,16)
        int bw = ibase + 20 * 15 + 16;
        float accb = cbv;
        #pragma unroll
        for (int ic = 0; ic < 2; ic++)
            #pragma unroll
            for (int ki = 0; ki < 3; ki++)
                #pragma unroll
                for (int kj = 0; kj < 3; kj++)
                    accb = fmaf(lds[ic][bw + 20 * ki + kj], wgt[ic * 9 + ki * 3 + kj].x, accb);
        s += accb; q = fmaf(accb, accb, q);
    }

    // reduce within each 16-lane (img,o) group
    #pragma unroll
    for (int off = 8; off > 0; off >>= 1) {
        s += __shfl_down(s, off, 16);
        q += __shfl_down(q, off, 16);
    }
    if (p == 0) {
        int rep = b & 31;
        atomicAdd(&ws[WS_SUMR + rep * 128 + c * 2 + o], s);
        atomicAdd(&ws[WS_SQR  + rep * 128 + c * 2 + o], q);
    }
}

// ---------------- Prep: replica-sum stats, BN scale/shift, folded fc weights ----------------
__global__ __launch_bounds__(128) void prep_kernel(
    const float* __restrict__ bn_g, const float* __restrict__ bn_b,
    const float* __restrict__ fc1_w, const float* __restrict__ fc1_b,
    const float* __restrict__ fc2_w, const float* __restrict__ fc2_b,
    const float* __restrict__ w_out,
    float* __restrict__ ws)
{
    int c = blockIdx.x;
    int f = threadIdx.x;

    float wsum = 0.f;
    #pragma unroll
    for (int h = 0; h < 8; h++)
        wsum += fc2_w[c * 8 + h] * fc1_w[(c * 8 + h) * 128 + f];
    ws[WS_WF + c * 128 + f] = w_out[c] * wsum;

    if (f == 0) {
        float bsum = fc2_b[c];
        #pragma unroll
        for (int h = 0; h < 8; h++)
            bsum += fc2_w[c * 8 + h] * fc1_b[c * 8 + h];
        ws[WS_WB + c] = w_out[c] * bsum;
    }
    if (f < 2) {
        int idx = c * 2 + f;
        float s = 0.f, q = 0.f;
        for (int r = 0; r < 32; r++) {
            s += ws[WS_SUMR + r * 128 + idx];
            q += ws[WS_SQR  + r * 128 + idx];
        }
        const float N = 2048.0f * 289.0f;
        float mean = s / N;
        float var  = q / N - mean * mean;
        float inv  = rsqrtf(var + EPS);
        float A    = bn_g[idx] * inv;
        ws[WS_A + idx] = A;
        ws[WS_B + idx] = bn_b[idx] - mean * A;
    }
}

// ---------------- Pass 2: stream bf16 pool -> logits -> sigmoid ----------------
__global__ __launch_bounds__(256) void pass2_kernel(
    const float* __restrict__ ws, const float* __restrict__ b_out,
    float* __restrict__ out)
{
    __shared__ float red[4];
    int b = blockIdx.x;
    int t = threadIdx.x;
    const uint4* pool = (const uint4*)(ws + WS_POOL) + (size_t)b * 2048;

    float partial = (t < 64) ? ws[WS_WB + t] : 0.f;
    if (t == 0) partial += b_out[0];

    #pragma unroll
    for (int i = 0; i < 8; i++) {
        uint4 p = pool[t + i * 256];
        int k0 = (t + i * 256) * 4;
        float A  = ws[WS_A + (k0 >> 6)];
        float Bs = ws[WS_B + (k0 >> 6)];
        const float4 wf = *(const float4*)&ws[WS_WF + k0];
        unsigned uu[4] = { p.x, p.y, p.z, p.w };
        float wfv[4] = { wf.x, wf.y, wf.z, wf.w };
        #pragma unroll
        for (int j = 0; j < 4; j++) {
            float mx = __uint_as_float(uu[j] & 0xffff0000u);
            float mn = __uint_as_float(uu[j] << 16);
            float val = A > 0.f ? mx : mn;
            float v = fmaf(A, val, Bs);
            v = v > 0.f ? v : SLOPE * v;
            partial = fmaf(v, wfv[j], partial);
        }
    }

    #pragma unroll
    for (int off = 32; off > 0; off >>= 1)
        partial += __shfl_down(partial, off);
    if ((t & 63) == 0) red[t >> 6] = partial;
    __syncthreads();
    if (t == 0) {
        float lsum = red[0] + red[1] + red[2] + red[3];
        out[b] = 1.f / (1.f + expf(-lsum));
    }
}

// ---------------- Fallback path (small ws): recompute conv with BN applied ----------------
__global__ __launch_bounds__(128) void main_fb_kernel(
    const float* __restrict__ x1, const float* __restrict__ x2,
    const float* __restrict__ conv_w, const float* __restrict__ conv_b,
    float* __restrict__ ws)
{
    __shared__ float lds[2][19 * 20];
    __shared__ float red[2];

    int blk = blockIdx.x;
    int c = blk & 63;
    int b = blk >> 6;
    int t = threadIdx.x;

    const float* src1 = x1 + (size_t)blk * 361;
    const float* src2 = x2 + (size_t)blk * 361;
    for (int i = t; i < 361; i += 128) {
        int r = i / 19;
        int col = i - r * 19;
        lds[0][r * 20 + col] = src1[i];
        lds[1][r * 20 + col] = src2[i];
    }

    int o = t >> 6;
    int l = t & 63;
    int pi = l >> 3, pj = l & 7;

    const float* wcp = conv_w + c * 36 + o * 18;
    float w0[9], w1[9];
    #pragma unroll
    for (int k = 0; k < 9; k++) { w0[k] = wcp[k]; w1[k] = wcp[9 + k]; }
    float cbv = conv_b[c * 2 + o];
    float A   = ws[WS_A + c * 2 + o];
    float Bs  = ws[WS_B + c * 2 + o];
    float wf  = ws[WS_WF + c * 128 + t];

    __syncthreads();

    float xw[2][4][4];
    int base = (2 * pi) * 20 + 2 * pj;
    #pragma unroll
    for (int ic = 0; ic < 2; ic++)
        #pragma unroll
        for (int r = 0; r < 4; r++)
            #pragma unroll
            for (int cc = 0; cc < 4; cc++)
                xw[ic][r][cc] = lds[ic][base + r * 20 + cc];

    float m = -3.4e38f;
    #pragma unroll
    for (int di = 0; di < 2; di++)
        #pragma unroll
        for (int dj = 0; dj < 2; dj++) {
            float acc = cbv;
            #pragma unroll
            for (int ki = 0; ki < 3; ki++)
                #pragma unroll
                for (int kj = 0; kj < 3; kj++) {
                    acc = fmaf(xw[0][di + ki][dj + kj], w0[ki * 3 + kj], acc);
                    acc = fmaf(xw[1][di + ki][dj + kj], w1[ki * 3 + kj], acc);
                }
            float v = fmaf(A, acc, Bs);
            v = v > 0.f ? v : SLOPE * v;
            m = fmaxf(m, v);
        }

    float contrib = m * wf;
    #pragma unroll
    for (int off = 32; off > 0; off >>= 1)
        contrib += __shfl_down(contrib, off);
    if (l == 0) red[o] = contrib;
    __syncthreads();
    if (t == 0)
        atomicAdd(&ws[WS_LOGIT + b], red[0] + red[1]);
}

__global__ __launch_bounds__(256) void final_fb_kernel(
    const float* __restrict__ ws, const float* __restrict__ b_out,
    float* __restrict__ out)
{
    int b = blockIdx.x * blockDim.x + threadIdx.x;
    if (b >= BATCH) return;
    float bias = b_out[0];
    #pragma unroll
    for (int c = 0; c < CC; c++) bias += ws[WS_WB + c];
    float l = ws[WS_LOGIT + b] + bias;
    out[b] = 1.f / (1.f + expf(-l));
}

extern "C" void kernel_launch(void* const* d_in, const int* in_sizes, int n_in,
                              void* d_out, int out_size, void* d_ws, size_t ws_size,
                              hipStream_t stream) {
    const float* x1     = (const float*)d_in[0];
    const float* x2     = (const float*)d_in[1];
    const float* conv_w = (const float*)d_in[2];
    const float* conv_b = (const float*)d_in[3];
    const float* bn_g   = (const float*)d_in[4];
    const float* bn_b   = (const float*)d_in[5];
    const float* fc1_w  = (const float*)d_in[6];
    const float* fc1_b  = (const float*)d_in[7];
    const float* fc2_w  = (const float*)d_in[8];
    const float* fc2_b  = (const float*)d_in[9];
    const float* w_out  = (const float*)d_in[10];
    const float* b_out  = (const float*)d_in[11];
    float* ws  = (float*)d_ws;
    float* out = (float*)d_out;

    dim3 big(BATCH * 32);            // 1 wave per block, 2 images per wave
    bool pool_path = ws_size >= WS_NEEDED_BYTES;

    if (pool_path) {
        hipMemsetAsync(d_ws, 0, 8192 * sizeof(float), stream);   // stats replicas
        pass1_kernel<true><<<big, 64, 0, stream>>>(x1, x2, conv_w, conv_b, ws);
        prep_kernel<<<CC, 128, 0, stream>>>(bn_g, bn_b, fc1_w, fc1_b, fc2_w, fc2_b, w_out, ws);
        pass2_kernel<<<BATCH, 256, 0, stream>>>(ws, b_out, out);
    } else {
        hipMemsetAsync(d_ws, 0, 18752 * sizeof(float), stream);  // stats + logits
        pass1_kernel<false><<<big, 64, 0, stream>>>(x1, x2, conv_w, conv_b, ws);
        prep_kernel<<<CC, 128, 0, stream>>>(bn_g, bn_b, fc1_w, fc1_b, fc2_w, fc2_b, w_out, ws);
        main_fb_kernel<<<dim3(BATCH * CC), 128, 0, stream>>>(x1, x2, conv_w, conv_b, ws);
        final_fb_kernel<<<(BATCH + 255) / 256, 256, 0, stream>>>(ws, b_out, out);
    }
}